// Round 7
// baseline (184.945 us; speedup 1.0000x reference)
//
#include <hip/hip_runtime.h>
#include <math.h>

#define T_LEN 2048
#define NB 2
#define E_DIM 1024
#define F_DIM 1536
#define HQn 16
#define HKn 4
#define Dh 64
#define WIN 1024
#define GATE_CH 12
#define PS 72   // LDS row stride (elems): 144B, 16B-aligned

typedef unsigned short u16;
typedef unsigned int u32;
typedef __attribute__((ext_vector_type(8))) short bf16x8;
typedef __attribute__((ext_vector_type(4))) short bf16x4;
typedef __attribute__((ext_vector_type(4))) float f32x4;

// K=16 bf16 MFMA: probe builtin names; asm fallback (instr exists on gfx950).
#if __has_builtin(__builtin_amdgcn_mfma_f32_16x16x16bf16_1k)
#define MFMA16(A, B, C) __builtin_amdgcn_mfma_f32_16x16x16bf16_1k(A, B, C, 0, 0, 0)
#elif __has_builtin(__builtin_amdgcn_mfma_f32_16x16x16_bf16)
#define MFMA16(A, B, C) __builtin_amdgcn_mfma_f32_16x16x16_bf16(A, B, C, 0, 0, 0)
#else
static __device__ __forceinline__ f32x4 mfma16_asm(bf16x4 a, bf16x4 b, f32x4 c) {
  f32x4 d;
  asm volatile("s_nop 1\n\tv_mfma_f32_16x16x16_bf16 %0, %1, %2, %3\n\ts_nop 7\n\ts_nop 7"
               : "=v"(d) : "v"(a), "v"(b), "v"(c));
  return d;
}
#define MFMA16(A, B, C) mfma16_asm(A, B, C)
#endif

__device__ __forceinline__ u16 f2bf(float f) {
  union { float f; unsigned int u; } v; v.f = f;
  unsigned int u = v.u + 0x7FFF + ((v.u >> 16) & 1);
  return (u16)(u >> 16);
}
__device__ __forceinline__ float bf2f(u16 h) {
  union { unsigned int u; float f; } v; v.u = ((unsigned int)h) << 16;
  return v.f;
}
// pack two f32 -> two bf16 (round-half-up) in ONE v_perm + 2 adds
__device__ __forceinline__ u32 pack_bf2(float hi, float lo) {
  union { float f; u32 u; } a, b; a.f = hi; b.f = lo;
  return __builtin_amdgcn_perm(a.u + 0x8000u, b.u + 0x8000u, 0x07060302u);
}

// ---------------------------------------------------------------------------
// fp32 -> bf16 (RNE) for the two weight matrices in ONE launch.
// blocks [0,1536) -> wqkv, [1536,2560) -> wo
// ---------------------------------------------------------------------------
__global__ __launch_bounds__(256) void cvt_w(
    const float4* __restrict__ wqkv, const float4* __restrict__ wo,
    uint2* __restrict__ wqb, uint2* __restrict__ wob)
{
  int blk = blockIdx.x;
  const float4* in; uint2* out; int i;
  if (blk < 1536) { in = wqkv; out = wqb; i = blk * 256 + threadIdx.x; }
  else            { in = wo;   out = wob; i = (blk - 1536) * 256 + threadIdx.x; }
  float4 v = in[i];
  uint2 o;
  o.x = (unsigned)f2bf(v.x) | ((unsigned)f2bf(v.y) << 16);
  o.y = (unsigned)f2bf(v.z) | ((unsigned)f2bf(v.w) << 16);
  out[i] = o;
}

// ---------------------------------------------------------------------------
// bf16 MFMA GEMM v2: C[M][N] = A[M][K] * B[N][K]^T
// Single-barrier double-buffered LDS with register prefetch (attn-v3 pattern:
// global loads for tile k+1 in flight across compute on tile k; LDS store
// after compute; ONE __syncthreads per K-step — no async-LDS vmcnt(0) drain).
// AF32: A is fp32 in global, packed to bf16 (v_perm) during LDS store.
// 4 waves 2x2; wave tile (BM/2)x(BN/2); BK=32.
// ---------------------------------------------------------------------------
template<int BM, int BN, int AF32, int STORE_BF16>
__global__ __launch_bounds__(256) void gemm_dbuf(
    const void* __restrict__ Av, const u16* __restrict__ B,
    void* __restrict__ Cv, int M, int N, int K)
{
  constexpr int MI = BM / 32, NJ = BN / 32;
  constexpr int NSA = BM * 4 / 256;      // 8-elem A slots per thread
  constexpr int NSB = BN * 4 / 256;      // 8-elem B slots per thread
  __shared__ u16 As[2][BM * 32];
  __shared__ u16 Bs[2][BN * 32];
  const int tid = threadIdx.x;
  const int wave = tid >> 6, lane = tid & 63;
  const int quad = lane >> 4, lanelow = lane & 15;
  const int row0 = blockIdx.x * BM;
  const int col0 = blockIdx.y * BN;
  const int wm = (wave >> 1) * (BM / 2), wn = (wave & 1) * (BN / 2);

  const float* Af = (const float*)Av;
  const u16*  Ah = (const u16*)Av;

  f32x4 acc[MI][NJ];
#pragma unroll
  for (int i = 0; i < MI; ++i)
#pragma unroll
    for (int j = 0; j < NJ; ++j) acc[i][j] = (f32x4){0.f, 0.f, 0.f, 0.f};

  int arow[NSA], acol[NSA];
#pragma unroll
  for (int s = 0; s < NSA; ++s) {
    int slot = tid + s * 256;
    arow[s] = slot >> 2; acol[s] = (slot & 3) * 8;
  }
  int brow[NSB], bcol[NSB];
#pragma unroll
  for (int s = 0; s < NSB; ++s) {
    int slot = tid + s * 256;
    brow[s] = slot >> 2; bcol[s] = (slot & 3) * 8;
  }

  uint4 aU[NSA]; float4 aF0[NSA], aF1[NSA];
  uint4 bU[NSB];

  auto loadT = [&](int k0) {
#pragma unroll
    for (int s = 0; s < NSA; ++s) {
      if (AF32) {
        const float* p = Af + (size_t)(row0 + arow[s]) * K + k0 + acol[s];
        aF0[s] = *(const float4*)p;
        aF1[s] = *(const float4*)(p + 4);
      } else {
        aU[s] = *(const uint4*)(Ah + (size_t)(row0 + arow[s]) * K + k0 + acol[s]);
      }
    }
#pragma unroll
    for (int s = 0; s < NSB; ++s)
      bU[s] = *(const uint4*)(B + (size_t)(col0 + brow[s]) * K + k0 + bcol[s]);
  };
  auto storeT = [&](int buf) {
#pragma unroll
    for (int s = 0; s < NSA; ++s) {
      uint4 w;
      if (AF32) {
        w.x = pack_bf2(aF0[s].y, aF0[s].x);
        w.y = pack_bf2(aF0[s].w, aF0[s].z);
        w.z = pack_bf2(aF1[s].y, aF1[s].x);
        w.w = pack_bf2(aF1[s].w, aF1[s].z);
      } else {
        w = aU[s];
      }
      *(uint4*)&As[buf][arow[s] * 32 + acol[s]] = w;
    }
#pragma unroll
    for (int s = 0; s < NSB; ++s)
      *(uint4*)&Bs[buf][brow[s] * 32 + bcol[s]] = bU[s];
  };

  loadT(0);
  storeT(0);

  for (int k0 = 0; k0 < K; k0 += 32) {
    const int buf = (k0 >> 5) & 1;
    const bool more = (k0 + 32) < K;
    if (more) loadT(k0 + 32);          // prefetch in flight during compute
    __syncthreads();                   // LDS[buf] writes visible everywhere

    bf16x8 a[MI], b[NJ];
#pragma unroll
    for (int i = 0; i < MI; ++i)
      a[i] = *(const bf16x8*)&As[buf][(wm + i * 16 + lanelow) * 32 + quad * 8];
#pragma unroll
    for (int j = 0; j < NJ; ++j)
      b[j] = *(const bf16x8*)&Bs[buf][(wn + j * 16 + lanelow) * 32 + quad * 8];
#pragma unroll
    for (int i = 0; i < MI; ++i)
#pragma unroll
      for (int j = 0; j < NJ; ++j)
        acc[i][j] = __builtin_amdgcn_mfma_f32_16x16x32_bf16(a[i], b[j], acc[i][j], 0, 0, 0);

    if (more) storeT(buf ^ 1);         // safe: buf^1 last read before barrier
  }

#pragma unroll
  for (int i = 0; i < MI; ++i)
#pragma unroll
    for (int j = 0; j < NJ; ++j) {
      int r = row0 + wm + i * 16 + quad * 4;
      int c = col0 + wn + j * 16 + lanelow;
#pragma unroll
      for (int reg = 0; reg < 4; ++reg) {
        if (STORE_BF16)
          ((u16*)Cv)[(size_t)(r + reg) * N + c] = f2bf(acc[i][j][reg]);
        else
          ((float*)Cv)[(size_t)(r + reg) * N + c] = acc[i][j][reg];
      }
    }
}

// ---------------------------------------------------------------------------
// postproc: gate = 3*sigmoid(x[:,:12]@wg^T); RoPE+RMS on q,k; v += gate*ve.
// ---------------------------------------------------------------------------
__global__ __launch_bounds__(256) void postproc_bf(
    const u16* __restrict__ qkv, const float* __restrict__ x,
    const float* __restrict__ ve, const float* __restrict__ rcos,
    const float* __restrict__ rsin, const float* __restrict__ wg,
    u16* __restrict__ qa, u16* __restrict__ ka, u16* __restrict__ va)
{
  const int token = blockIdx.x;
  const int t = token & (T_LEN - 1);
  const int tid = threadIdx.x;
  const int wave = tid >> 6, lane = tid & 63;
  __shared__ float gate[HKn];
  if (tid < HKn) {
    float g = 0.f;
#pragma unroll
    for (int c = 0; c < GATE_CH; ++c)
      g += x[(size_t)token * E_DIM + c] * wg[tid * GATE_CH + c];
    gate[tid] = 3.f / (1.f + __expf(-g));
  }
  __syncthreads();
  const int half = lane & 31;
  for (int vi = wave; vi < HQn + HKn; vi += 4) {
    const u16* p = qkv + (size_t)token * F_DIM + vi * Dh;
    float c = rcos[t * 32 + half], s = rsin[t * 32 + half];
    float x1 = bf2f(p[half]), x2 = bf2f(p[half + 32]);
    float y = (lane < 32) ? (x1 * c - x2 * s) : (x1 * s + x2 * c);
    float ss = y * y;
#pragma unroll
    for (int o = 32; o; o >>= 1) ss += __shfl_xor(ss, o, 64);
    float v = y * rsqrtf(ss * (1.f / Dh) + 1e-8f);
    if (vi < HQn)
      qa[((size_t)token * HQn + vi) * Dh + lane] = f2bf(v * 0.1803368801f); // 0.125*log2(e)
    else
      ka[((size_t)token * HKn + (vi - HQn)) * Dh + lane] = f2bf(v);
  }
  {
    float g = gate[tid >> 6];
    size_t vidx = (size_t)token * (HKn * Dh) + tid;
    va[vidx] = f2bf(bf2f(qkv[(size_t)token * F_DIM + (HQn + HKn) * Dh + tid]) + g * ve[vidx]);
  }
}

// ---------------------------------------------------------------------------
// V transpose: va[tok][hk][d] -> vt[(b*4+hk)*64 + d][t]
// ---------------------------------------------------------------------------
__global__ __launch_bounds__(256) void transpose_v(
    const u16* __restrict__ va, u16* __restrict__ vt)
{
  __shared__ u16 tile[64][PS];
  const int bhk = blockIdx.y;
  const int b = bhk >> 2, hk = bhk & 3;
  const int t0 = blockIdx.x * 64;
  const int tid = threadIdx.x;
#pragma unroll
  for (int p = 0; p < 2; ++p) {
    int s = tid + p * 256;
    int r = s >> 3, seg = s & 7;
    *(uint4*)&tile[r][seg * 8] =
        *(const uint4*)(va + ((size_t)(b * T_LEN + t0 + r) * HKn + hk) * Dh + seg * 8);
  }
  __syncthreads();
#pragma unroll
  for (int p = 0; p < 2; ++p) {
    int s = tid + p * 256;
    int d = s >> 3, seg = s & 7;
    u16 tmp[8];
#pragma unroll
    for (int e = 0; e < 8; ++e) tmp[e] = tile[seg * 8 + e][d];
    *(uint4*)(vt + ((size_t)bhk * Dh + d) * T_LEN + t0 + seg * 8) = *(uint4*)tmp;
  }
}

// ---------------------------------------------------------------------------
// MFMA flash attention v4 (unchanged from R6): 64-row q-tiles, S^T
// formulation (P in registers as B-operand of K=16 MFMA), fixed-shift
// softmax, double-buffered K/V with register prefetch, 1 barrier/k-tile.
// ---------------------------------------------------------------------------
__global__ __launch_bounds__(256) void attn_mfma(
    const u16* __restrict__ qa, const u16* __restrict__ ka,
    const u16* __restrict__ vt_g, u16* __restrict__ att)
{
  __shared__ u16 Ks[2][64 * PS];   // [buf][j][d]
  __shared__ u16 Vt[2][64 * PS];   // [buf][d][j]
  const int qt = blockIdx.x, h = blockIdx.y, b = blockIdx.z;
  const int hk = h >> 2;
  const int qb = qt * 64;
  const int tid = threadIdx.x;
  const int wave = tid >> 6, lane = tid & 63;
  const int quad = lane >> 4, lanelow = lane & 15;

  bf16x8 aQ[2];
#pragma unroll
  for (int kk = 0; kk < 2; ++kk)
    aQ[kk] = *(const bf16x8*)(qa +
        ((size_t)(b * T_LEN + qb + wave * 16 + lanelow) * HQn + h) * Dh +
        kk * 32 + quad * 8);

  f32x4 O[4];
  float l = 0.f;
#pragma unroll
  for (int dt = 0; dt < 4; ++dt) O[dt] = (f32x4){0.f, 0.f, 0.f, 0.f};

  const int kt0 = (qt >= 16) ? qt - 16 : 0;
  const int kt1 = qt;

  const int sr0 = tid >> 3,         sc0 = (tid & 7) * 8;
  const int sr1 = (tid + 256) >> 3, sc1 = ((tid + 256) & 7) * 8;
  const u16* kg = ka + (size_t)(b * T_LEN) * (HKn * Dh) + hk * Dh;
  const u16* vg = vt_g + (size_t)(b * HKn + hk) * Dh * T_LEN;

  {
    const int kb = kt0 * 64;
    uint4 k0 = *(const uint4*)(kg + (size_t)(kb + sr0) * (HKn * Dh) + sc0);
    uint4 k1 = *(const uint4*)(kg + (size_t)(kb + sr1) * (HKn * Dh) + sc1);
    uint4 v0 = *(const uint4*)(vg + (size_t)sr0 * T_LEN + kb + sc0);
    uint4 v1 = *(const uint4*)(vg + (size_t)sr1 * T_LEN + kb + sc1);
    *(uint4*)&Ks[0][sr0 * PS + sc0] = k0;
    *(uint4*)&Ks[0][sr1 * PS + sc1] = k1;
    *(uint4*)&Vt[0][sr0 * PS + sc0] = v0;
    *(uint4*)&Vt[0][sr1 * PS + sc1] = v1;
  }

  for (int kt = kt0; kt <= kt1; ++kt) {
    const int buf = (kt - kt0) & 1;
    const int kb = kt * 64;
    uint4 k0, k1, v0, v1;
    const bool more = (kt < kt1);
    if (more) {
      const int nb = kb + 64;
      k0 = *(const uint4*)(kg + (size_t)(nb + sr0) * (HKn * Dh) + sc0);
      k1 = *(const uint4*)(kg + (size_t)(nb + sr1) * (HKn * Dh) + sc1);
      v0 = *(const uint4*)(vg + (size_t)sr0 * T_LEN + nb + sc0);
      v1 = *(const uint4*)(vg + (size_t)sr1 * T_LEN + nb + sc1);
    }
    __syncthreads();

    f32x4 St[4];
#pragma unroll
    for (int jt = 0; jt < 4; ++jt) {
      bf16x8 aK0 = *(const bf16x8*)&Ks[buf][(jt * 16 + lanelow) * PS + quad * 8];
      bf16x8 aK1 = *(const bf16x8*)&Ks[buf][(jt * 16 + lanelow) * PS + 32 + quad * 8];
      f32x4 acc = (f32x4){-12.f, -12.f, -12.f, -12.f};
      acc = __builtin_amdgcn_mfma_f32_16x16x32_bf16(aK0, aQ[0], acc, 0, 0, 0);
      acc = __builtin_amdgcn_mfma_f32_16x16x32_bf16(aK1, aQ[1], acc, 0, 0, 0);
      St[jt] = acc;
    }
    if (kt == kt1) {
#pragma unroll
      for (int jt = 0; jt < 4; ++jt)
#pragma unroll
        for (int rr = 0; rr < 4; ++rr) {
          int ig = qb + wave * 16 + lanelow;
          int jg = kb + jt * 16 + quad * 4 + rr;
          if (jg > ig) St[jt][rr] = -1e30f;
        }
    } else if (kt == kt0 && qt >= 16) {
#pragma unroll
      for (int jt = 0; jt < 4; ++jt)
#pragma unroll
        for (int rr = 0; rr < 4; ++rr) {
          int ig = qb + wave * 16 + lanelow;
          int jg = kb + jt * 16 + quad * 4 + rr;
          if (jg < ig - WIN) St[jt][rr] = -1e30f;
        }
    }
    bf16x4 Pt[4];
#pragma unroll
    for (int jt = 0; jt < 4; ++jt) {
      float p0 = __builtin_amdgcn_exp2f(St[jt][0]);
      float p1 = __builtin_amdgcn_exp2f(St[jt][1]);
      float p2 = __builtin_amdgcn_exp2f(St[jt][2]);
      float p3 = __builtin_amdgcn_exp2f(St[jt][3]);
      l += (p0 + p1) + (p2 + p3);
      union { uint2 u; bf16x4 v; } pu;
      pu.u.x = pack_bf2(p1, p0);
      pu.u.y = pack_bf2(p3, p2);
      Pt[jt] = pu.v;
    }
#pragma unroll
    for (int dt = 0; dt < 4; ++dt)
#pragma unroll
      for (int jt = 0; jt < 4; ++jt) {
        bf16x4 aV = *(const bf16x4*)&Vt[buf][(dt * 16 + lanelow) * PS + jt * 16 + quad * 4];
        O[dt] = MFMA16(aV, Pt[jt], O[dt]);
      }
    if (more) {
      const int nbuf = buf ^ 1;
      *(uint4*)&Ks[nbuf][sr0 * PS + sc0] = k0;
      *(uint4*)&Ks[nbuf][sr1 * PS + sc1] = k1;
      *(uint4*)&Vt[nbuf][sr0 * PS + sc0] = v0;
      *(uint4*)&Vt[nbuf][sr1 * PS + sc1] = v1;
    }
  }

  {
    float s = l;
    s += __shfl_xor(s, 16, 64);
    s += __shfl_xor(s, 32, 64);
    float inv = 1.f / s;
    int qg = qb + wave * 16 + lanelow;
    u16* obase = att + (size_t)(b * T_LEN + qg) * E_DIM + h * Dh;
#pragma unroll
    for (int dt = 0; dt < 4; ++dt) {
      bf16x4 ov;
      ov[0] = (short)f2bf(O[dt][0] * inv);
      ov[1] = (short)f2bf(O[dt][1] * inv);
      ov[2] = (short)f2bf(O[dt][2] * inv);
      ov[3] = (short)f2bf(O[dt][3] * inv);
      *(bf16x4*)(obase + dt * 16 + quad * 4) = ov;
    }
  }
}

// ---------------------------------------------------------------------------
extern "C" void kernel_launch(void* const* d_in, const int* in_sizes, int n_in,
                              void* d_out, int out_size, void* d_ws, size_t ws_size,
                              hipStream_t stream)
{
  const float* x    = (const float*)d_in[0];
  const float* ve   = (const float*)d_in[1];
  const float* rc   = (const float*)d_in[2];
  const float* rs   = (const float*)d_in[3];
  const float* wqkv = (const float*)d_in[4];
  const float* wg   = (const float*)d_in[5];
  const float* wo   = (const float*)d_in[6];
  float* out = (float*)d_out;

  char* ws = (char*)d_ws;
  u16* v_t     = (u16*)(ws);                       //  2 MB  512x2048
  u16* wqkv_bf = (u16*)(ws + 2097152);             //  3 MB  1536x1024
  u16* wo_bf   = (u16*)(ws + 5242880);             //  2 MB  1024x1024
  u16* qkv_bf  = (u16*)(ws + 7340032);             // 12 MB  4096x1536
  u16* att     = qkv_bf;                           //  8 MB  (reuse, dead after postproc)
  u16* q_att   = (u16*)(ws + 19922944);            //  8 MB  4096x16x64
  u16* k_att   = (u16*)(ws + 28311552);            //  2 MB  4096x4x64
  u16* v_att   = (u16*)(ws + 30408704);            //  2 MB  4096x4x64

  // 1) weight conversions (x converted inline by gemm1)
  cvt_w<<<2560, 256, 0, stream>>>((const float4*)wqkv, (const float4*)wo,
                                  (uint2*)wqkv_bf, (uint2*)wo_bf);
  // 2) QKV projection, fp32 A staged+converted in-kernel
  gemm_dbuf<128, 64, 1, 1><<<dim3(32, 24), 256, 0, stream>>>(
      x, wqkv_bf, qkv_bf, 4096, F_DIM, E_DIM);
  // 3) gate + value-embed + RoPE + RMS -> packed bf16 q/k/v
  postproc_bf<<<NB * T_LEN, 256, 0, stream>>>(qkv_bf, x, ve, rc, rs, wg, q_att, k_att, v_att);
  // 4) V transpose for attn staging
  transpose_v<<<dim3(32, 8), 256, 0, stream>>>(v_att, v_t);
  // 5) MFMA flash attention
  attn_mfma<<<dim3(T_LEN / 64, HQn, NB), 256, 0, stream>>>(q_att, k_att, v_t, att);
  // 6) output projection, fp32 out
  gemm_dbuf<64, 64, 0, 0><<<dim3(64, 16), 256, 0, stream>>>(
      att, wo_bf, out, 4096, E_DIM, E_DIM);
}

// Round 9
// 177.078 us; speedup vs baseline: 1.0444x; 1.0444x over previous
//
#include <hip/hip_runtime.h>
#include <math.h>

#define T_LEN 2048
#define NB 2
#define E_DIM 1024
#define F_DIM 1536
#define HQn 16
#define HKn 4
#define Dh 64
#define WIN 1024
#define GATE_CH 12
#define PS 72   // LDS row stride (elems): 144B, 16B-aligned

typedef unsigned short u16;
typedef unsigned int u32;
typedef __attribute__((ext_vector_type(8))) short bf16x8;
typedef __attribute__((ext_vector_type(4))) short bf16x4;
typedef __attribute__((ext_vector_type(4))) float f32x4;

// K=16 bf16 MFMA: probe builtin names; asm fallback (instr exists on gfx950).
#if __has_builtin(__builtin_amdgcn_mfma_f32_16x16x16bf16_1k)
#define MFMA16(A, B, C) __builtin_amdgcn_mfma_f32_16x16x16bf16_1k(A, B, C, 0, 0, 0)
#elif __has_builtin(__builtin_amdgcn_mfma_f32_16x16x16_bf16)
#define MFMA16(A, B, C) __builtin_amdgcn_mfma_f32_16x16x16_bf16(A, B, C, 0, 0, 0)
#else
static __device__ __forceinline__ f32x4 mfma16_asm(bf16x4 a, bf16x4 b, f32x4 c) {
  f32x4 d;
  asm volatile("s_nop 1\n\tv_mfma_f32_16x16x16_bf16 %0, %1, %2, %3\n\ts_nop 7\n\ts_nop 7"
               : "=v"(d) : "v"(a), "v"(b), "v"(c));
  return d;
}
#define MFMA16(A, B, C) mfma16_asm(A, B, C)
#endif

__device__ __forceinline__ u16 f2bf(float f) {
  union { float f; unsigned int u; } v; v.f = f;
  unsigned int u = v.u + 0x7FFF + ((v.u >> 16) & 1);
  return (u16)(u >> 16);
}
__device__ __forceinline__ float bf2f(u16 h) {
  union { unsigned int u; float f; } v; v.u = ((unsigned int)h) << 16;
  return v.f;
}
// pack two f32 -> two bf16 (round-half-up) in ONE v_perm + 2 adds
__device__ __forceinline__ u32 pack_bf2(float hi, float lo) {
  union { float f; u32 u; } a, b; a.f = hi; b.f = lo;
  return __builtin_amdgcn_perm(a.u + 0x8000u, b.u + 0x8000u, 0x07060302u);
}
__device__ __forceinline__ void async_copy16(const void* g, void* l) {
  __builtin_amdgcn_global_load_lds(
      (const __attribute__((address_space(1))) unsigned int*)g,
      (__attribute__((address_space(3))) unsigned int*)l, 16, 0, 0);
}

// ---------------------------------------------------------------------------
// fp32 -> bf16 (RNE) for x / wqkv / wo in ONE launch.
// blocks [0,4096) x | [4096,5632) wqkv | [5632,6656) wo
// ---------------------------------------------------------------------------
__global__ __launch_bounds__(256) void cvt_all(
    const float4* __restrict__ x, const float4* __restrict__ wqkv,
    const float4* __restrict__ wo, uint2* __restrict__ xb,
    uint2* __restrict__ wqb, uint2* __restrict__ wob)
{
  int blk = blockIdx.x;
  const float4* in; uint2* out; int i;
  if (blk < 4096)       { in = x;    out = xb;  i = blk * 256 + threadIdx.x; }
  else if (blk < 5632)  { in = wqkv; out = wqb; i = (blk - 4096) * 256 + threadIdx.x; }
  else                  { in = wo;   out = wob; i = (blk - 5632) * 256 + threadIdx.x; }
  float4 v = in[i];
  uint2 o;
  o.x = (unsigned)f2bf(v.x) | ((unsigned)f2bf(v.y) << 16);
  o.y = (unsigned)f2bf(v.z) | ((unsigned)f2bf(v.w) << 16);
  out[i] = o;
}

// ---------------------------------------------------------------------------
// bf16 MFMA GEMM v3: C[M][N] = A[M][K] * B[N][K]^T.  BK=64 via TWO stride-32
// LDS arrays per operand (each is the proven bank-clean m97 layout; a naive
// stride-64 row would 16-way-conflict ds_read_b128). One barrier pair now
// amortizes 6 global_load_lds + 16 MFMAs/wave — half the barrier/drain count
// of BK=32. 4 waves 2x2; wave tile (BM/2)x(BN/2).
// LDS dst = s*4096 + wave*1024 + lane*16 bytes = wave-uniform + lane*16 ✓.
// ---------------------------------------------------------------------------
template<int BM, int BN, int STORE_BF16>
__global__ __launch_bounds__(256) void gemm_async(
    const u16* __restrict__ A, const u16* __restrict__ B,
    void* __restrict__ Cv, int M, int N, int K)
{
  constexpr int MI = BM / 32, NJ = BN / 32;
  constexpr int NSA = BM / 64;     // A slots per thread per kk-half
  constexpr int NSB = BN / 64;
  __shared__ u16 As[2][BM * 32];   // [kk][row*32 + seg*8]
  __shared__ u16 Bs[2][BN * 32];
  const int tid = threadIdx.x;
  const int wave = tid >> 6, lane = tid & 63;
  const int quad = lane >> 4, lanelow = lane & 15;
  const int row0 = blockIdx.x * BM;
  const int col0 = blockIdx.y * BN;
  const int wm = (wave >> 1) * (BM / 2), wn = (wave & 1) * (BN / 2);

  f32x4 acc[MI][NJ];
#pragma unroll
  for (int i = 0; i < MI; ++i)
#pragma unroll
    for (int j = 0; j < NJ; ++j) acc[i][j] = (f32x4){0.f, 0.f, 0.f, 0.f};

  for (int k0 = 0; k0 < K; k0 += 64) {
    __syncthreads();
#pragma unroll
    for (int kk = 0; kk < 2; ++kk) {
#pragma unroll
      for (int s = 0; s < NSA; ++s) {
        int slot = s * 256 + tid;
        async_copy16(A + (size_t)(row0 + (slot >> 2)) * K + k0 + kk * 32 + (slot & 3) * 8,
                     &As[kk][slot * 8]);
      }
#pragma unroll
      for (int s = 0; s < NSB; ++s) {
        int slot = s * 256 + tid;
        async_copy16(B + (size_t)(col0 + (slot >> 2)) * K + k0 + kk * 32 + (slot & 3) * 8,
                     &Bs[kk][slot * 8]);
      }
    }
    __syncthreads();
#pragma unroll
    for (int kk = 0; kk < 2; ++kk) {
      bf16x8 a[MI], b[NJ];
#pragma unroll
      for (int i = 0; i < MI; ++i)
        a[i] = *(const bf16x8*)&As[kk][(wm + i * 16 + lanelow) * 32 + quad * 8];
#pragma unroll
      for (int j = 0; j < NJ; ++j)
        b[j] = *(const bf16x8*)&Bs[kk][(wn + j * 16 + lanelow) * 32 + quad * 8];
#pragma unroll
      for (int i = 0; i < MI; ++i)
#pragma unroll
        for (int j = 0; j < NJ; ++j)
          acc[i][j] = __builtin_amdgcn_mfma_f32_16x16x32_bf16(a[i], b[j], acc[i][j], 0, 0, 0);
    }
  }

#pragma unroll
  for (int i = 0; i < MI; ++i)
#pragma unroll
    for (int j = 0; j < NJ; ++j) {
      int r = row0 + wm + i * 16 + quad * 4;
      int c = col0 + wn + j * 16 + lanelow;
#pragma unroll
      for (int reg = 0; reg < 4; ++reg) {
        if (STORE_BF16)
          ((u16*)Cv)[(size_t)(r + reg) * N + c] = f2bf(acc[i][j][reg]);
        else
          ((float*)Cv)[(size_t)(r + reg) * N + c] = acc[i][j][reg];
      }
    }
}

// ---------------------------------------------------------------------------
// postproc: gate = 3*sigmoid(x[:,:12]@wg^T); RoPE+RMS on q,k; v += gate*ve.
// ---------------------------------------------------------------------------
__global__ __launch_bounds__(256) void postproc_bf(
    const u16* __restrict__ qkv, const float* __restrict__ x,
    const float* __restrict__ ve, const float* __restrict__ rcos,
    const float* __restrict__ rsin, const float* __restrict__ wg,
    u16* __restrict__ qa, u16* __restrict__ ka, u16* __restrict__ va)
{
  const int token = blockIdx.x;
  const int t = token & (T_LEN - 1);
  const int tid = threadIdx.x;
  const int wave = tid >> 6, lane = tid & 63;
  __shared__ float gate[HKn];
  if (tid < HKn) {
    float g = 0.f;
#pragma unroll
    for (int c = 0; c < GATE_CH; ++c)
      g += x[(size_t)token * E_DIM + c] * wg[tid * GATE_CH + c];
    gate[tid] = 3.f / (1.f + __expf(-g));
  }
  __syncthreads();
  const int half = lane & 31;
  for (int vi = wave; vi < HQn + HKn; vi += 4) {
    const u16* p = qkv + (size_t)token * F_DIM + vi * Dh;
    float c = rcos[t * 32 + half], s = rsin[t * 32 + half];
    float x1 = bf2f(p[half]), x2 = bf2f(p[half + 32]);
    float y = (lane < 32) ? (x1 * c - x2 * s) : (x1 * s + x2 * c);
    float ss = y * y;
#pragma unroll
    for (int o = 32; o; o >>= 1) ss += __shfl_xor(ss, o, 64);
    float v = y * rsqrtf(ss * (1.f / Dh) + 1e-8f);
    if (vi < HQn)
      qa[((size_t)token * HQn + vi) * Dh + lane] = f2bf(v * 0.1803368801f); // 0.125*log2(e)
    else
      ka[((size_t)token * HKn + (vi - HQn)) * Dh + lane] = f2bf(v);
  }
  {
    float g = gate[tid >> 6];
    size_t vidx = (size_t)token * (HKn * Dh) + tid;
    va[vidx] = f2bf(bf2f(qkv[(size_t)token * F_DIM + (HQn + HKn) * Dh + tid]) + g * ve[vidx]);
  }
}

// ---------------------------------------------------------------------------
// V transpose: va[tok][hk][d] -> vt[(b*4+hk)*64 + d][t]
// ---------------------------------------------------------------------------
__global__ __launch_bounds__(256) void transpose_v(
    const u16* __restrict__ va, u16* __restrict__ vt)
{
  __shared__ u16 tile[64][PS];
  const int bhk = blockIdx.y;
  const int b = bhk >> 2, hk = bhk & 3;
  const int t0 = blockIdx.x * 64;
  const int tid = threadIdx.x;
#pragma unroll
  for (int p = 0; p < 2; ++p) {
    int s = tid + p * 256;
    int r = s >> 3, seg = s & 7;
    *(uint4*)&tile[r][seg * 8] =
        *(const uint4*)(va + ((size_t)(b * T_LEN + t0 + r) * HKn + hk) * Dh + seg * 8);
  }
  __syncthreads();
#pragma unroll
  for (int p = 0; p < 2; ++p) {
    int s = tid + p * 256;
    int d = s >> 3, seg = s & 7;
    u16 tmp[8];
#pragma unroll
    for (int e = 0; e < 8; ++e) tmp[e] = tile[seg * 8 + e][d];
    *(uint4*)(vt + ((size_t)bhk * Dh + d) * T_LEN + t0 + seg * 8) = *(uint4*)tmp;
  }
}

// ---------------------------------------------------------------------------
// MFMA flash attention v4 (unchanged): 64-row q-tiles, S^T formulation
// (P in registers as B-operand of K=16 MFMA), fixed-shift softmax,
// double-buffered K/V with register prefetch, 1 barrier/k-tile.
// ---------------------------------------------------------------------------
__global__ __launch_bounds__(256) void attn_mfma(
    const u16* __restrict__ qa, const u16* __restrict__ ka,
    const u16* __restrict__ vt_g, u16* __restrict__ att)
{
  __shared__ u16 Ks[2][64 * PS];   // [buf][j][d]
  __shared__ u16 Vt[2][64 * PS];   // [buf][d][j]
  const int qt = blockIdx.x, h = blockIdx.y, b = blockIdx.z;
  const int hk = h >> 2;
  const int qb = qt * 64;
  const int tid = threadIdx.x;
  const int wave = tid >> 6, lane = tid & 63;
  const int quad = lane >> 4, lanelow = lane & 15;

  bf16x8 aQ[2];
#pragma unroll
  for (int kk = 0; kk < 2; ++kk)
    aQ[kk] = *(const bf16x8*)(qa +
        ((size_t)(b * T_LEN + qb + wave * 16 + lanelow) * HQn + h) * Dh +
        kk * 32 + quad * 8);

  f32x4 O[4];
  float l = 0.f;
#pragma unroll
  for (int dt = 0; dt < 4; ++dt) O[dt] = (f32x4){0.f, 0.f, 0.f, 0.f};

  const int kt0 = (qt >= 16) ? qt - 16 : 0;
  const int kt1 = qt;

  const int sr0 = tid >> 3,         sc0 = (tid & 7) * 8;
  const int sr1 = (tid + 256) >> 3, sc1 = ((tid + 256) & 7) * 8;
  const u16* kg = ka + (size_t)(b * T_LEN) * (HKn * Dh) + hk * Dh;
  const u16* vg = vt_g + (size_t)(b * HKn + hk) * Dh * T_LEN;

  {
    const int kb = kt0 * 64;
    uint4 k0 = *(const uint4*)(kg + (size_t)(kb + sr0) * (HKn * Dh) + sc0);
    uint4 k1 = *(const uint4*)(kg + (size_t)(kb + sr1) * (HKn * Dh) + sc1);
    uint4 v0 = *(const uint4*)(vg + (size_t)sr0 * T_LEN + kb + sc0);
    uint4 v1 = *(const uint4*)(vg + (size_t)sr1 * T_LEN + kb + sc1);
    *(uint4*)&Ks[0][sr0 * PS + sc0] = k0;
    *(uint4*)&Ks[0][sr1 * PS + sc1] = k1;
    *(uint4*)&Vt[0][sr0 * PS + sc0] = v0;
    *(uint4*)&Vt[0][sr1 * PS + sc1] = v1;
  }

  for (int kt = kt0; kt <= kt1; ++kt) {
    const int buf = (kt - kt0) & 1;
    const int kb = kt * 64;
    uint4 k0, k1, v0, v1;
    const bool more = (kt < kt1);
    if (more) {
      const int nb = kb + 64;
      k0 = *(const uint4*)(kg + (size_t)(nb + sr0) * (HKn * Dh) + sc0);
      k1 = *(const uint4*)(kg + (size_t)(nb + sr1) * (HKn * Dh) + sc1);
      v0 = *(const uint4*)(vg + (size_t)sr0 * T_LEN + nb + sc0);
      v1 = *(const uint4*)(vg + (size_t)sr1 * T_LEN + nb + sc1);
    }
    __syncthreads();

    f32x4 St[4];
#pragma unroll
    for (int jt = 0; jt < 4; ++jt) {
      bf16x8 aK0 = *(const bf16x8*)&Ks[buf][(jt * 16 + lanelow) * PS + quad * 8];
      bf16x8 aK1 = *(const bf16x8*)&Ks[buf][(jt * 16 + lanelow) * PS + 32 + quad * 8];
      f32x4 acc = (f32x4){-12.f, -12.f, -12.f, -12.f};
      acc = __builtin_amdgcn_mfma_f32_16x16x32_bf16(aK0, aQ[0], acc, 0, 0, 0);
      acc = __builtin_amdgcn_mfma_f32_16x16x32_bf16(aK1, aQ[1], acc, 0, 0, 0);
      St[jt] = acc;
    }
    if (kt == kt1) {
#pragma unroll
      for (int jt = 0; jt < 4; ++jt)
#pragma unroll
        for (int rr = 0; rr < 4; ++rr) {
          int ig = qb + wave * 16 + lanelow;
          int jg = kb + jt * 16 + quad * 4 + rr;
          if (jg > ig) St[jt][rr] = -1e30f;
        }
    } else if (kt == kt0 && qt >= 16) {
#pragma unroll
      for (int jt = 0; jt < 4; ++jt)
#pragma unroll
        for (int rr = 0; rr < 4; ++rr) {
          int ig = qb + wave * 16 + lanelow;
          int jg = kb + jt * 16 + quad * 4 + rr;
          if (jg < ig - WIN) St[jt][rr] = -1e30f;
        }
    }
    bf16x4 Pt[4];
#pragma unroll
    for (int jt = 0; jt < 4; ++jt) {
      float p0 = __builtin_amdgcn_exp2f(St[jt][0]);
      float p1 = __builtin_amdgcn_exp2f(St[jt][1]);
      float p2 = __builtin_amdgcn_exp2f(St[jt][2]);
      float p3 = __builtin_amdgcn_exp2f(St[jt][3]);
      l += (p0 + p1) + (p2 + p3);
      union { uint2 u; bf16x4 v; } pu;
      pu.u.x = pack_bf2(p1, p0);
      pu.u.y = pack_bf2(p3, p2);
      Pt[jt] = pu.v;
    }
#pragma unroll
    for (int dt = 0; dt < 4; ++dt)
#pragma unroll
      for (int jt = 0; jt < 4; ++jt) {
        bf16x4 aV = *(const bf16x4*)&Vt[buf][(dt * 16 + lanelow) * PS + jt * 16 + quad * 4];
        O[dt] = MFMA16(aV, Pt[jt], O[dt]);
      }
    if (more) {
      const int nbuf = buf ^ 1;
      *(uint4*)&Ks[nbuf][sr0 * PS + sc0] = k0;
      *(uint4*)&Ks[nbuf][sr1 * PS + sc1] = k1;
      *(uint4*)&Vt[nbuf][sr0 * PS + sc0] = v0;
      *(uint4*)&Vt[nbuf][sr1 * PS + sc1] = v1;
    }
  }

  {
    float s = l;
    s += __shfl_xor(s, 16, 64);
    s += __shfl_xor(s, 32, 64);
    float inv = 1.f / s;
    int qg = qb + wave * 16 + lanelow;
    u16* obase = att + (size_t)(b * T_LEN + qg) * E_DIM + h * Dh;
#pragma unroll
    for (int dt = 0; dt < 4; ++dt) {
      bf16x4 ov;
      ov[0] = (short)f2bf(O[dt][0] * inv);
      ov[1] = (short)f2bf(O[dt][1] * inv);
      ov[2] = (short)f2bf(O[dt][2] * inv);
      ov[3] = (short)f2bf(O[dt][3] * inv);
      *(bf16x4*)(obase + dt * 16 + quad * 4) = ov;
    }
  }
}

// ---------------------------------------------------------------------------
extern "C" void kernel_launch(void* const* d_in, const int* in_sizes, int n_in,
                              void* d_out, int out_size, void* d_ws, size_t ws_size,
                              hipStream_t stream)
{
  const float* x    = (const float*)d_in[0];
  const float* ve   = (const float*)d_in[1];
  const float* rc   = (const float*)d_in[2];
  const float* rs   = (const float*)d_in[3];
  const float* wqkv = (const float*)d_in[4];
  const float* wg   = (const float*)d_in[5];
  const float* wo   = (const float*)d_in[6];
  float* out = (float*)d_out;

  char* ws = (char*)d_ws;
  // ws layout (DISJOINT ranges; R8's bug was k/v_att inside q_att):
  //   [0,        8388608)  x_bf (v_t reuses first 2 MB after gemm1)
  //   [8388608, 11534336)  wqkv_bf
  //   [11534336,13631488)  wo_bf
  //   [13631488,26214400)  qkv_bf (att reuses after postproc)
  //   [26214400,34603008)  q_att
  //   [34603008,36700160)  k_att
  //   [36700160,38797312)  v_att
  u16* x_bf    = (u16*)(ws);
  u16* v_t     = x_bf;
  u16* wqkv_bf = (u16*)(ws + 8388608);
  u16* wo_bf   = (u16*)(ws + 11534336);
  u16* qkv_bf  = (u16*)(ws + 13631488);
  u16* att     = qkv_bf;
  u16* q_att   = (u16*)(ws + 26214400);
  u16* k_att   = (u16*)(ws + 34603008);
  u16* v_att   = (u16*)(ws + 36700160);

  cvt_all<<<6656, 256, 0, stream>>>((const float4*)x, (const float4*)wqkv,
                                    (const float4*)wo, (uint2*)x_bf,
                                    (uint2*)wqkv_bf, (uint2*)wo_bf);
  gemm_async<128, 64, 1><<<dim3(32, 24), 256, 0, stream>>>(
      x_bf, wqkv_bf, qkv_bf, 4096, F_DIM, E_DIM);
  postproc_bf<<<NB * T_LEN, 256, 0, stream>>>(qkv_bf, x, ve, rc, rs, wg,
                                              q_att, k_att, v_att);
  transpose_v<<<dim3(32, 8), 256, 0, stream>>>(v_att, v_t);
  attn_mfma<<<dim3(T_LEN / 64, HQn, NB), 256, 0, stream>>>(q_att, k_att, v_t, att);
  gemm_async<64, 64, 0><<<dim3(64, 16), 256, 0, stream>>>(
      att, wo_bf, out, 4096, E_DIM, E_DIM);
}

// Round 10
// 174.555 us; speedup vs baseline: 1.0595x; 1.0145x over previous
//
#include <hip/hip_runtime.h>
#include <math.h>

#define T_LEN 2048
#define NB 2
#define E_DIM 1024
#define F_DIM 1536
#define HQn 16
#define HKn 4
#define Dh 64
#define WIN 1024
#define GATE_CH 12
#define PS 72   // LDS row stride (elems) for attn tiles: 144B, 16B-aligned
#define CS 73   // LDS row stride for gemm1 epilogue C-tile (odd: bank spread)

typedef unsigned short u16;
typedef unsigned int u32;
typedef __attribute__((ext_vector_type(8))) short bf16x8;
typedef __attribute__((ext_vector_type(4))) short bf16x4;
typedef __attribute__((ext_vector_type(4))) float f32x4;

// K=16 bf16 MFMA: probe builtin names; asm fallback (instr exists on gfx950).
#if __has_builtin(__builtin_amdgcn_mfma_f32_16x16x16bf16_1k)
#define MFMA16(A, B, C) __builtin_amdgcn_mfma_f32_16x16x16bf16_1k(A, B, C, 0, 0, 0)
#elif __has_builtin(__builtin_amdgcn_mfma_f32_16x16x16_bf16)
#define MFMA16(A, B, C) __builtin_amdgcn_mfma_f32_16x16x16_bf16(A, B, C, 0, 0, 0)
#else
static __device__ __forceinline__ f32x4 mfma16_asm(bf16x4 a, bf16x4 b, f32x4 c) {
  f32x4 d;
  asm volatile("s_nop 1\n\tv_mfma_f32_16x16x16_bf16 %0, %1, %2, %3\n\ts_nop 7\n\ts_nop 7"
               : "=v"(d) : "v"(a), "v"(b), "v"(c));
  return d;
}
#define MFMA16(A, B, C) mfma16_asm(A, B, C)
#endif

__device__ __forceinline__ u16 f2bf(float f) {
  union { float f; unsigned int u; } v; v.f = f;
  unsigned int u = v.u + 0x7FFF + ((v.u >> 16) & 1);
  return (u16)(u >> 16);
}
__device__ __forceinline__ float bf2f(u16 h) {
  union { unsigned int u; float f; } v; v.u = ((unsigned int)h) << 16;
  return v.f;
}
// pack two f32 -> two bf16 (round-half-up) in ONE v_perm + 2 adds
__device__ __forceinline__ u32 pack_bf2(float hi, float lo) {
  union { float f; u32 u; } a, b; a.f = hi; b.f = lo;
  return __builtin_amdgcn_perm(a.u + 0x8000u, b.u + 0x8000u, 0x07060302u);
}
__device__ __forceinline__ void async_copy16(const void* g, void* l) {
  __builtin_amdgcn_global_load_lds(
      (const __attribute__((address_space(1))) unsigned int*)g,
      (__attribute__((address_space(3))) unsigned int*)l, 16, 0, 0);
}

// ---------------------------------------------------------------------------
// fp32 -> bf16 (RNE) for x / wqkv / wo in ONE launch.
// blocks [0,4096) x | [4096,5632) wqkv | [5632,6656) wo
// ---------------------------------------------------------------------------
__global__ __launch_bounds__(256) void cvt_all(
    const float4* __restrict__ x, const float4* __restrict__ wqkv,
    const float4* __restrict__ wo, uint2* __restrict__ xb,
    uint2* __restrict__ wqb, uint2* __restrict__ wob)
{
  int blk = blockIdx.x;
  const float4* in; uint2* out; int i;
  if (blk < 4096)       { in = x;    out = xb;  i = blk * 256 + threadIdx.x; }
  else if (blk < 5632)  { in = wqkv; out = wqb; i = (blk - 4096) * 256 + threadIdx.x; }
  else                  { in = wo;   out = wob; i = (blk - 5632) * 256 + threadIdx.x; }
  float4 v = in[i];
  uint2 o;
  o.x = (unsigned)f2bf(v.x) | ((unsigned)f2bf(v.y) << 16);
  o.y = (unsigned)f2bf(v.z) | ((unsigned)f2bf(v.w) << 16);
  out[i] = o;
}

// ---------------------------------------------------------------------------
// QKV GEMM + FUSED postproc epilogue.
// C-tile = 128 tokens x 64 dims = one full head per block (BN=64=Dh, and
// blockIdx.y = head index: 0-15 q, 16-19 k, 20-23 v). K-loop identical to the
// R9 BK=64 structure. Epilogue: acc -> LDS Ct[128][CS] (bf16, same rounding as
// the old qkv_bf round-trip), then per head type:
//   q/k: RoPE + RMS (64-lane shuffle reduce) -> q_att / k_att
//   v:   gate=3*sigmoid(x[:,:12]@wg^T); +gate*ve; LDS transpose -> v_t[d][t]
// Eliminates postproc + transpose_v kernels and the 25 MB qkv round-trip.
// ---------------------------------------------------------------------------
__global__ __launch_bounds__(256) void gemm_qkv(
    const u16* __restrict__ A, const u16* __restrict__ B,
    const float* __restrict__ x, const float* __restrict__ ve,
    const float* __restrict__ rcos, const float* __restrict__ rsin,
    const float* __restrict__ wg,
    u16* __restrict__ qa, u16* __restrict__ ka, u16* __restrict__ vt)
{
  constexpr int K = E_DIM;
  __shared__ u16 smem[12288];           // 24 KB: staging As/Bs, then Ct
  __shared__ float gateL[128];
  u16* As = smem;                       // [2][128*32]
  u16* Bs = smem + 8192;                // [2][64*32]
  u16* Ct = smem;                       // [128][CS] = 9344 u16 (reuse)
  const int tid = threadIdx.x;
  const int wave = tid >> 6, lane = tid & 63;
  const int quad = lane >> 4, lanelow = lane & 15;
  const int row0 = blockIdx.x * 128;    // token base
  const int h    = blockIdx.y;          // head 0..23
  const int col0 = h * 64;
  const int wm = (wave >> 1) * 64, wn = (wave & 1) * 32;

  f32x4 acc[4][2];
#pragma unroll
  for (int i = 0; i < 4; ++i)
#pragma unroll
    for (int j = 0; j < 2; ++j) acc[i][j] = (f32x4){0.f, 0.f, 0.f, 0.f};

  for (int k0 = 0; k0 < K; k0 += 64) {
    __syncthreads();
#pragma unroll
    for (int kk = 0; kk < 2; ++kk) {
#pragma unroll
      for (int s = 0; s < 2; ++s) {
        int slot = s * 256 + tid;
        async_copy16(A + (size_t)(row0 + (slot >> 2)) * K + k0 + kk * 32 + (slot & 3) * 8,
                     &As[kk * 4096 + slot * 8]);
      }
      {
        int slot = tid;
        async_copy16(B + (size_t)(col0 + (slot >> 2)) * K + k0 + kk * 32 + (slot & 3) * 8,
                     &Bs[kk * 2048 + slot * 8]);
      }
    }
    __syncthreads();
#pragma unroll
    for (int kk = 0; kk < 2; ++kk) {
      bf16x8 a[4], b[2];
#pragma unroll
      for (int i = 0; i < 4; ++i)
        a[i] = *(const bf16x8*)&As[kk * 4096 + (wm + i * 16 + lanelow) * 32 + quad * 8];
#pragma unroll
      for (int j = 0; j < 2; ++j)
        b[j] = *(const bf16x8*)&Bs[kk * 2048 + (wn + j * 16 + lanelow) * 32 + quad * 8];
#pragma unroll
      for (int i = 0; i < 4; ++i)
#pragma unroll
        for (int j = 0; j < 2; ++j)
          acc[i][j] = __builtin_amdgcn_mfma_f32_16x16x32_bf16(a[i], b[j], acc[i][j], 0, 0, 0);
    }
  }

  // ---- fused epilogue ----
  __syncthreads();                      // all LDS frag reads done; reuse smem
#pragma unroll
  for (int i = 0; i < 4; ++i)
#pragma unroll
    for (int j = 0; j < 2; ++j)
#pragma unroll
      for (int reg = 0; reg < 4; ++reg) {
        int row = wm + i * 16 + quad * 4 + reg;
        int col = wn + j * 16 + lanelow;
        Ct[row * CS + col] = f2bf(acc[i][j][reg]);
      }
  __syncthreads();

  if (h < HQn + HKn) {                  // q or k head: RoPE + RMS
    const bool isq = (h < HQn);
    const int half = lane & 31;
    for (int t = wave * 32; t < wave * 32 + 32; ++t) {
      int tok = row0 + t;
      int tt = tok & (T_LEN - 1);
      float c = rcos[tt * 32 + half], s = rsin[tt * 32 + half];
      float x1 = bf2f(Ct[t * CS + half]);
      float x2 = bf2f(Ct[t * CS + half + 32]);
      float y = (lane < 32) ? (x1 * c - x2 * s) : (x1 * s + x2 * c);
      float ss = y * y;
#pragma unroll
      for (int o = 32; o; o >>= 1) ss += __shfl_xor(ss, o, 64);
      float v = y * rsqrtf(ss * (1.f / Dh) + 1e-8f);
      if (isq)
        qa[((size_t)tok * HQn + h) * Dh + lane] = f2bf(v * 0.1803368801f); // 0.125*log2(e)
      else
        ka[((size_t)tok * HKn + (h - HQn)) * Dh + lane] = f2bf(v);
    }
  } else {                              // v head: gate + ve, transposed store
    const int hk = h - (HQn + HKn);
    if (tid < 128) {
      int tok = row0 + tid;
      float g = 0.f;
#pragma unroll
      for (int c = 0; c < GATE_CH; ++c)
        g += x[(size_t)tok * E_DIM + c] * wg[hk * GATE_CH + c];
      gateL[tid] = 3.f / (1.f + __expf(-g));
    }
    __syncthreads();
    for (int t = wave * 32; t < wave * 32 + 32; ++t) {
      int tok = row0 + t;
      float val = bf2f(Ct[t * CS + lane]) +
                  gateL[t] * ve[(size_t)tok * (HKn * Dh) + hk * Dh + lane];
      Ct[t * CS + lane] = f2bf(val);
    }
    __syncthreads();
    // transposed readout: thread -> (d, 32-token segment)
    int d = tid >> 2, tseg = (tid & 3) * 32;
    int tokbase = row0 + tseg;
    int b = tokbase >> 11;              // uniform per block (128 | 2048)
    int tloc = tokbase & (T_LEN - 1);
    u16 tmp[32];
#pragma unroll
    for (int e = 0; e < 32; ++e) tmp[e] = Ct[(tseg + e) * CS + d];
    u16* dst = vt + ((size_t)(b * HKn + hk) * Dh + d) * T_LEN + tloc;
#pragma unroll
    for (int p = 0; p < 4; ++p)
      *(uint4*)(dst + p * 8) = *(uint4*)&tmp[p * 8];
  }
}

// ---------------------------------------------------------------------------
// bf16 MFMA GEMM (R9 BK=64 structure) for the output projection.
// ---------------------------------------------------------------------------
template<int BM, int BN, int STORE_BF16>
__global__ __launch_bounds__(256) void gemm_async(
    const u16* __restrict__ A, const u16* __restrict__ B,
    void* __restrict__ Cv, int M, int N, int K)
{
  constexpr int MI = BM / 32, NJ = BN / 32;
  constexpr int NSA = BM / 64;
  constexpr int NSB = BN / 64;
  __shared__ u16 As[2][BM * 32];
  __shared__ u16 Bs[2][BN * 32];
  const int tid = threadIdx.x;
  const int wave = tid >> 6, lane = tid & 63;
  const int quad = lane >> 4, lanelow = lane & 15;
  const int row0 = blockIdx.x * BM;
  const int col0 = blockIdx.y * BN;
  const int wm = (wave >> 1) * (BM / 2), wn = (wave & 1) * (BN / 2);

  f32x4 acc[MI][NJ];
#pragma unroll
  for (int i = 0; i < MI; ++i)
#pragma unroll
    for (int j = 0; j < NJ; ++j) acc[i][j] = (f32x4){0.f, 0.f, 0.f, 0.f};

  for (int k0 = 0; k0 < K; k0 += 64) {
    __syncthreads();
#pragma unroll
    for (int kk = 0; kk < 2; ++kk) {
#pragma unroll
      for (int s = 0; s < NSA; ++s) {
        int slot = s * 256 + tid;
        async_copy16(A + (size_t)(row0 + (slot >> 2)) * K + k0 + kk * 32 + (slot & 3) * 8,
                     &As[kk][slot * 8]);
      }
#pragma unroll
      for (int s = 0; s < NSB; ++s) {
        int slot = s * 256 + tid;
        async_copy16(B + (size_t)(col0 + (slot >> 2)) * K + k0 + kk * 32 + (slot & 3) * 8,
                     &Bs[kk][slot * 8]);
      }
    }
    __syncthreads();
#pragma unroll
    for (int kk = 0; kk < 2; ++kk) {
      bf16x8 a[MI], b[NJ];
#pragma unroll
      for (int i = 0; i < MI; ++i)
        a[i] = *(const bf16x8*)&As[kk][(wm + i * 16 + lanelow) * 32 + quad * 8];
#pragma unroll
      for (int j = 0; j < NJ; ++j)
        b[j] = *(const bf16x8*)&Bs[kk][(wn + j * 16 + lanelow) * 32 + quad * 8];
#pragma unroll
      for (int i = 0; i < MI; ++i)
#pragma unroll
        for (int j = 0; j < NJ; ++j)
          acc[i][j] = __builtin_amdgcn_mfma_f32_16x16x32_bf16(a[i], b[j], acc[i][j], 0, 0, 0);
    }
  }

#pragma unroll
  for (int i = 0; i < MI; ++i)
#pragma unroll
    for (int j = 0; j < NJ; ++j) {
      int r = row0 + wm + i * 16 + quad * 4;
      int c = col0 + wn + j * 16 + lanelow;
#pragma unroll
      for (int reg = 0; reg < 4; ++reg) {
        if (STORE_BF16)
          ((u16*)Cv)[(size_t)(r + reg) * N + c] = f2bf(acc[i][j][reg]);
        else
          ((float*)Cv)[(size_t)(r + reg) * N + c] = acc[i][j][reg];
      }
    }
}

// ---------------------------------------------------------------------------
// MFMA flash attention (unchanged from R9): 64-row q-tiles, S^T formulation
// (P in registers as B-operand of K=16 MFMA), fixed-shift softmax,
// double-buffered K/V with register prefetch, 1 barrier/k-tile.
// ---------------------------------------------------------------------------
__global__ __launch_bounds__(256) void attn_mfma(
    const u16* __restrict__ qa, const u16* __restrict__ ka,
    const u16* __restrict__ vt_g, u16* __restrict__ att)
{
  __shared__ u16 Ks[2][64 * PS];   // [buf][j][d]
  __shared__ u16 Vt[2][64 * PS];   // [buf][d][j]
  const int qt = blockIdx.x, h = blockIdx.y, b = blockIdx.z;
  const int hk = h >> 2;
  const int qb = qt * 64;
  const int tid = threadIdx.x;
  const int wave = tid >> 6, lane = tid & 63;
  const int quad = lane >> 4, lanelow = lane & 15;

  bf16x8 aQ[2];
#pragma unroll
  for (int kk = 0; kk < 2; ++kk)
    aQ[kk] = *(const bf16x8*)(qa +
        ((size_t)(b * T_LEN + qb + wave * 16 + lanelow) * HQn + h) * Dh +
        kk * 32 + quad * 8);

  f32x4 O[4];
  float l = 0.f;
#pragma unroll
  for (int dt = 0; dt < 4; ++dt) O[dt] = (f32x4){0.f, 0.f, 0.f, 0.f};

  const int kt0 = (qt >= 16) ? qt - 16 : 0;
  const int kt1 = qt;

  const int sr0 = tid >> 3,         sc0 = (tid & 7) * 8;
  const int sr1 = (tid + 256) >> 3, sc1 = ((tid + 256) & 7) * 8;
  const u16* kg = ka + (size_t)(b * T_LEN) * (HKn * Dh) + hk * Dh;
  const u16* vg = vt_g + (size_t)(b * HKn + hk) * Dh * T_LEN;

  {
    const int kb = kt0 * 64;
    uint4 k0 = *(const uint4*)(kg + (size_t)(kb + sr0) * (HKn * Dh) + sc0);
    uint4 k1 = *(const uint4*)(kg + (size_t)(kb + sr1) * (HKn * Dh) + sc1);
    uint4 v0 = *(const uint4*)(vg + (size_t)sr0 * T_LEN + kb + sc0);
    uint4 v1 = *(const uint4*)(vg + (size_t)sr1 * T_LEN + kb + sc1);
    *(uint4*)&Ks[0][sr0 * PS + sc0] = k0;
    *(uint4*)&Ks[0][sr1 * PS + sc1] = k1;
    *(uint4*)&Vt[0][sr0 * PS + sc0] = v0;
    *(uint4*)&Vt[0][sr1 * PS + sc1] = v1;
  }

  for (int kt = kt0; kt <= kt1; ++kt) {
    const int buf = (kt - kt0) & 1;
    const int kb = kt * 64;
    uint4 k0, k1, v0, v1;
    const bool more = (kt < kt1);
    if (more) {
      const int nb = kb + 64;
      k0 = *(const uint4*)(kg + (size_t)(nb + sr0) * (HKn * Dh) + sc0);
      k1 = *(const uint4*)(kg + (size_t)(nb + sr1) * (HKn * Dh) + sc1);
      v0 = *(const uint4*)(vg + (size_t)sr0 * T_LEN + nb + sc0);
      v1 = *(const uint4*)(vg + (size_t)sr1 * T_LEN + nb + sc1);
    }
    __syncthreads();

    f32x4 St[4];
#pragma unroll
    for (int jt = 0; jt < 4; ++jt) {
      bf16x8 aK0 = *(const bf16x8*)&Ks[buf][(jt * 16 + lanelow) * PS + quad * 8];
      bf16x8 aK1 = *(const bf16x8*)&Ks[buf][(jt * 16 + lanelow) * PS + 32 + quad * 8];
      f32x4 acc = (f32x4){-12.f, -12.f, -12.f, -12.f};
      acc = __builtin_amdgcn_mfma_f32_16x16x32_bf16(aK0, aQ[0], acc, 0, 0, 0);
      acc = __builtin_amdgcn_mfma_f32_16x16x32_bf16(aK1, aQ[1], acc, 0, 0, 0);
      St[jt] = acc;
    }
    if (kt == kt1) {
#pragma unroll
      for (int jt = 0; jt < 4; ++jt)
#pragma unroll
        for (int rr = 0; rr < 4; ++rr) {
          int ig = qb + wave * 16 + lanelow;
          int jg = kb + jt * 16 + quad * 4 + rr;
          if (jg > ig) St[jt][rr] = -1e30f;
        }
    } else if (kt == kt0 && qt >= 16) {
#pragma unroll
      for (int jt = 0; jt < 4; ++jt)
#pragma unroll
        for (int rr = 0; rr < 4; ++rr) {
          int ig = qb + wave * 16 + lanelow;
          int jg = kb + jt * 16 + quad * 4 + rr;
          if (jg < ig - WIN) St[jt][rr] = -1e30f;
        }
    }
    bf16x4 Pt[4];
#pragma unroll
    for (int jt = 0; jt < 4; ++jt) {
      float p0 = __builtin_amdgcn_exp2f(St[jt][0]);
      float p1 = __builtin_amdgcn_exp2f(St[jt][1]);
      float p2 = __builtin_amdgcn_exp2f(St[jt][2]);
      float p3 = __builtin_amdgcn_exp2f(St[jt][3]);
      l += (p0 + p1) + (p2 + p3);
      union { uint2 u; bf16x4 v; } pu;
      pu.u.x = pack_bf2(p1, p0);
      pu.u.y = pack_bf2(p3, p2);
      Pt[jt] = pu.v;
    }
#pragma unroll
    for (int dt = 0; dt < 4; ++dt)
#pragma unroll
      for (int jt = 0; jt < 4; ++jt) {
        bf16x4 aV = *(const bf16x4*)&Vt[buf][(dt * 16 + lanelow) * PS + jt * 16 + quad * 4];
        O[dt] = MFMA16(aV, Pt[jt], O[dt]);
      }
    if (more) {
      const int nbuf = buf ^ 1;
      *(uint4*)&Ks[nbuf][sr0 * PS + sc0] = k0;
      *(uint4*)&Ks[nbuf][sr1 * PS + sc1] = k1;
      *(uint4*)&Vt[nbuf][sr0 * PS + sc0] = v0;
      *(uint4*)&Vt[nbuf][sr1 * PS + sc1] = v1;
    }
  }

  {
    float s = l;
    s += __shfl_xor(s, 16, 64);
    s += __shfl_xor(s, 32, 64);
    float inv = 1.f / s;
    int qg = qb + wave * 16 + lanelow;
    u16* obase = att + (size_t)(b * T_LEN + qg) * E_DIM + h * Dh;
#pragma unroll
    for (int dt = 0; dt < 4; ++dt) {
      bf16x4 ov;
      ov[0] = (short)f2bf(O[dt][0] * inv);
      ov[1] = (short)f2bf(O[dt][1] * inv);
      ov[2] = (short)f2bf(O[dt][2] * inv);
      ov[3] = (short)f2bf(O[dt][3] * inv);
      *(bf16x4*)(obase + dt * 16 + quad * 4) = ov;
    }
  }
}

// ---------------------------------------------------------------------------
extern "C" void kernel_launch(void* const* d_in, const int* in_sizes, int n_in,
                              void* d_out, int out_size, void* d_ws, size_t ws_size,
                              hipStream_t stream)
{
  const float* x    = (const float*)d_in[0];
  const float* ve   = (const float*)d_in[1];
  const float* rc   = (const float*)d_in[2];
  const float* rs   = (const float*)d_in[3];
  const float* wqkv = (const float*)d_in[4];
  const float* wg   = (const float*)d_in[5];
  const float* wo   = (const float*)d_in[6];
  float* out = (float*)d_out;

  char* ws = (char*)d_ws;
  // ws layout — ALL ranges disjoint (R8 lesson):
  //   [0,        8388608)  x_bf      4096x1024 bf16
  //   [8388608, 11534336)  wqkv_bf   1536x1024 bf16
  //   [11534336,13631488)  wo_bf     1024x1024 bf16
  //   [13631488,22020096)  q_att     4096x16x64 bf16
  //   [22020096,24117248)  k_att     4096x4x64 bf16
  //   [24117248,26214400)  v_t       (2*4*64)x2048 bf16
  //   [26214400,34603008)  att       4096x1024 bf16
  u16* x_bf    = (u16*)(ws);
  u16* wqkv_bf = (u16*)(ws + 8388608);
  u16* wo_bf   = (u16*)(ws + 11534336);
  u16* q_att   = (u16*)(ws + 13631488);
  u16* k_att   = (u16*)(ws + 22020096);
  u16* v_t     = (u16*)(ws + 24117248);
  u16* att     = (u16*)(ws + 26214400);

  cvt_all<<<6656, 256, 0, stream>>>((const float4*)x, (const float4*)wqkv,
                                    (const float4*)wo, (uint2*)x_bf,
                                    (uint2*)wqkv_bf, (uint2*)wo_bf);
  gemm_qkv<<<dim3(32, 24), 256, 0, stream>>>(x_bf, wqkv_bf, x, ve, rc, rs, wg,
                                             q_att, k_att, v_t);
  attn_mfma<<<dim3(T_LEN / 64, HQn, NB), 256, 0, stream>>>(q_att, k_att, v_t, att);
  gemm_async<64, 64, 0><<<dim3(64, 16), 256, 0, stream>>>(
      att, wo_bf, out, 4096, E_DIM, E_DIM);
}

// Round 11
// 168.718 us; speedup vs baseline: 1.0962x; 1.0346x over previous
//
#include <hip/hip_runtime.h>
#include <math.h>

#define T_LEN 2048
#define NB 2
#define E_DIM 1024
#define F_DIM 1536
#define HQn 16
#define HKn 4
#define Dh 64
#define WIN 1024
#define GATE_CH 12
#define PS 72   // LDS row stride (elems) for attn tiles: 144B, 16B-aligned
#define CS 73   // LDS row stride for gemm1 epilogue C-tile (odd: bank spread)

typedef unsigned short u16;
typedef unsigned int u32;
typedef __attribute__((ext_vector_type(8))) short bf16x8;
typedef __attribute__((ext_vector_type(4))) short bf16x4;
typedef __attribute__((ext_vector_type(4))) float f32x4;

// K=16 bf16 MFMA: probe builtin names; asm fallback (instr exists on gfx950).
#if __has_builtin(__builtin_amdgcn_mfma_f32_16x16x16bf16_1k)
#define MFMA16(A, B, C) __builtin_amdgcn_mfma_f32_16x16x16bf16_1k(A, B, C, 0, 0, 0)
#elif __has_builtin(__builtin_amdgcn_mfma_f32_16x16x16_bf16)
#define MFMA16(A, B, C) __builtin_amdgcn_mfma_f32_16x16x16_bf16(A, B, C, 0, 0, 0)
#else
static __device__ __forceinline__ f32x4 mfma16_asm(bf16x4 a, bf16x4 b, f32x4 c) {
  f32x4 d;
  asm volatile("s_nop 1\n\tv_mfma_f32_16x16x16_bf16 %0, %1, %2, %3\n\ts_nop 7\n\ts_nop 7"
               : "=v"(d) : "v"(a), "v"(b), "v"(c));
  return d;
}
#define MFMA16(A, B, C) mfma16_asm(A, B, C)
#endif

__device__ __forceinline__ u16 f2bf(float f) {
  union { float f; unsigned int u; } v; v.f = f;
  unsigned int u = v.u + 0x7FFF + ((v.u >> 16) & 1);
  return (u16)(u >> 16);
}
__device__ __forceinline__ float bf2f(u16 h) {
  union { unsigned int u; float f; } v; v.u = ((unsigned int)h) << 16;
  return v.f;
}
// pack two f32 -> two bf16 (round-half-up) in ONE v_perm + 2 adds
__device__ __forceinline__ u32 pack_bf2(float hi, float lo) {
  union { float f; u32 u; } a, b; a.f = hi; b.f = lo;
  return __builtin_amdgcn_perm(a.u + 0x8000u, b.u + 0x8000u, 0x07060302u);
}
__device__ __forceinline__ void async_copy16(const void* g, void* l) {
  __builtin_amdgcn_global_load_lds(
      (const __attribute__((address_space(1))) unsigned int*)g,
      (__attribute__((address_space(3))) unsigned int*)l, 16, 0, 0);
}

// ---------------------------------------------------------------------------
// fp32 -> bf16 (RNE) for x / wqkv / wo in ONE launch.
// blocks [0,4096) x | [4096,5632) wqkv | [5632,6656) wo
// ---------------------------------------------------------------------------
__global__ __launch_bounds__(256) void cvt_all(
    const float4* __restrict__ x, const float4* __restrict__ wqkv,
    const float4* __restrict__ wo, uint2* __restrict__ xb,
    uint2* __restrict__ wqb, uint2* __restrict__ wob)
{
  int blk = blockIdx.x;
  const float4* in; uint2* out; int i;
  if (blk < 4096)       { in = x;    out = xb;  i = blk * 256 + threadIdx.x; }
  else if (blk < 5632)  { in = wqkv; out = wqb; i = (blk - 4096) * 256 + threadIdx.x; }
  else                  { in = wo;   out = wob; i = (blk - 5632) * 256 + threadIdx.x; }
  float4 v = in[i];
  uint2 o;
  o.x = (unsigned)f2bf(v.x) | ((unsigned)f2bf(v.y) << 16);
  o.y = (unsigned)f2bf(v.z) | ((unsigned)f2bf(v.w) << 16);
  out[i] = o;
}

// ---------------------------------------------------------------------------
// QKV GEMM + FUSED postproc epilogue. BM=64 (R11): grid 64x24 = 1536 blocks
// = 6 blocks/CU (LDS 16.6 KB), 24 waves/CU — the R10 profile showed 25%
// occupancy / both pipes idle, i.e. latency-bound on the barrier drains with
// only 3 blocks/CU. C-tile = 64 tokens x 1 head (blockIdx.y: 0-15 q, 16-19 k,
// 20-23 v). Epilogue: acc -> LDS Ct (bf16) then RoPE+RMS (q/k) or
// gate+ve+transpose (v), writing q_att/k_att/v_t directly.
// ---------------------------------------------------------------------------
__global__ __launch_bounds__(256) void gemm_qkv(
    const u16* __restrict__ A, const u16* __restrict__ B,
    const float* __restrict__ x, const float* __restrict__ ve,
    const float* __restrict__ rcos, const float* __restrict__ rsin,
    const float* __restrict__ wg,
    u16* __restrict__ qa, u16* __restrict__ ka, u16* __restrict__ vt)
{
  constexpr int K = E_DIM;
  __shared__ u16 smem[8192];            // 16 KB: As/Bs staging, then Ct
  __shared__ float gateL[64];
  u16* As = smem;                       // [2][64*32]
  u16* Bs = smem + 4096;                // [2][64*32]
  u16* Ct = smem;                       // [64][CS] = 4672 u16 (reuse)
  const int tid = threadIdx.x;
  const int wave = tid >> 6, lane = tid & 63;
  const int quad = lane >> 4, lanelow = lane & 15;
  const int row0 = blockIdx.x * 64;     // token base
  const int h    = blockIdx.y;          // head 0..23
  const int col0 = h * 64;
  const int wm = (wave >> 1) * 32, wn = (wave & 1) * 32;

  f32x4 acc[2][2];
#pragma unroll
  for (int i = 0; i < 2; ++i)
#pragma unroll
    for (int j = 0; j < 2; ++j) acc[i][j] = (f32x4){0.f, 0.f, 0.f, 0.f};

  for (int k0 = 0; k0 < K; k0 += 64) {
    __syncthreads();
#pragma unroll
    for (int kk = 0; kk < 2; ++kk) {
      // one 16B slot per thread per operand: row=tid>>2, kcol=(tid&3)*8
      // LDS dst = kk*4096B*? -> addr = (kk*2048 + tid*8)*2B: uniform + lane*16 ✓
      async_copy16(A + (size_t)(row0 + (tid >> 2)) * K + k0 + kk * 32 + (tid & 3) * 8,
                   &As[kk * 2048 + tid * 8]);
      async_copy16(B + (size_t)(col0 + (tid >> 2)) * K + k0 + kk * 32 + (tid & 3) * 8,
                   &Bs[kk * 2048 + tid * 8]);
    }
    __syncthreads();
#pragma unroll
    for (int kk = 0; kk < 2; ++kk) {
      bf16x8 a[2], b[2];
#pragma unroll
      for (int i = 0; i < 2; ++i)
        a[i] = *(const bf16x8*)&As[kk * 2048 + (wm + i * 16 + lanelow) * 32 + quad * 8];
#pragma unroll
      for (int j = 0; j < 2; ++j)
        b[j] = *(const bf16x8*)&Bs[kk * 2048 + (wn + j * 16 + lanelow) * 32 + quad * 8];
#pragma unroll
      for (int i = 0; i < 2; ++i)
#pragma unroll
        for (int j = 0; j < 2; ++j)
          acc[i][j] = __builtin_amdgcn_mfma_f32_16x16x32_bf16(a[i], b[j], acc[i][j], 0, 0, 0);
    }
  }

  // ---- fused epilogue ----
  __syncthreads();                      // all LDS frag reads done; reuse smem
#pragma unroll
  for (int i = 0; i < 2; ++i)
#pragma unroll
    for (int j = 0; j < 2; ++j)
#pragma unroll
      for (int reg = 0; reg < 4; ++reg) {
        int row = wm + i * 16 + quad * 4 + reg;
        int col = wn + j * 16 + lanelow;
        Ct[row * CS + col] = f2bf(acc[i][j][reg]);
      }
  __syncthreads();

  if (h < HQn + HKn) {                  // q or k head: RoPE + RMS
    const bool isq = (h < HQn);
    const int half = lane & 31;
    for (int t = wave * 16; t < wave * 16 + 16; ++t) {
      int tok = row0 + t;
      int tt = tok & (T_LEN - 1);
      float c = rcos[tt * 32 + half], s = rsin[tt * 32 + half];
      float x1 = bf2f(Ct[t * CS + half]);
      float x2 = bf2f(Ct[t * CS + half + 32]);
      float y = (lane < 32) ? (x1 * c - x2 * s) : (x1 * s + x2 * c);
      float ss = y * y;
#pragma unroll
      for (int o = 32; o; o >>= 1) ss += __shfl_xor(ss, o, 64);
      float v = y * rsqrtf(ss * (1.f / Dh) + 1e-8f);
      if (isq)
        qa[((size_t)tok * HQn + h) * Dh + lane] = f2bf(v * 0.1803368801f); // 0.125*log2(e)
      else
        ka[((size_t)tok * HKn + (h - HQn)) * Dh + lane] = f2bf(v);
    }
  } else {                              // v head: gate + ve, transposed store
    const int hk = h - (HQn + HKn);
    if (tid < 64) {
      int tok = row0 + tid;
      float g = 0.f;
#pragma unroll
      for (int c = 0; c < GATE_CH; ++c)
        g += x[(size_t)tok * E_DIM + c] * wg[hk * GATE_CH + c];
      gateL[tid] = 3.f / (1.f + __expf(-g));
    }
    __syncthreads();
    for (int t = wave * 16; t < wave * 16 + 16; ++t) {
      int tok = row0 + t;
      float val = bf2f(Ct[t * CS + lane]) +
                  gateL[t] * ve[(size_t)tok * (HKn * Dh) + hk * Dh + lane];
      Ct[t * CS + lane] = f2bf(val);
    }
    __syncthreads();
    // transposed readout: thread -> (d, 16-token segment)
    int d = tid >> 2, tseg = (tid & 3) * 16;
    int tokbase = row0 + tseg;
    int b = tokbase >> 11;              // uniform per block (64 | 2048)
    int tloc = tokbase & (T_LEN - 1);
    u16 tmp[16];
#pragma unroll
    for (int e = 0; e < 16; ++e) tmp[e] = Ct[(tseg + e) * CS + d];
    u16* dst = vt + ((size_t)(b * HKn + hk) * Dh + d) * T_LEN + tloc;
#pragma unroll
    for (int p = 0; p < 2; ++p)
      *(uint4*)(dst + p * 8) = *(uint4*)&tmp[p * 8];
  }
}

// ---------------------------------------------------------------------------
// bf16 MFMA GEMM (R9 BK=64 structure) for the output projection.
// ---------------------------------------------------------------------------
template<int BM, int BN, int STORE_BF16>
__global__ __launch_bounds__(256) void gemm_async(
    const u16* __restrict__ A, const u16* __restrict__ B,
    void* __restrict__ Cv, int M, int N, int K)
{
  constexpr int MI = BM / 32, NJ = BN / 32;
  constexpr int NSA = BM / 64;
  constexpr int NSB = BN / 64;
  __shared__ u16 As[2][BM * 32];
  __shared__ u16 Bs[2][BN * 32];
  const int tid = threadIdx.x;
  const int wave = tid >> 6, lane = tid & 63;
  const int quad = lane >> 4, lanelow = lane & 15;
  const int row0 = blockIdx.x * BM;
  const int col0 = blockIdx.y * BN;
  const int wm = (wave >> 1) * (BM / 2), wn = (wave & 1) * (BN / 2);

  f32x4 acc[MI][NJ];
#pragma unroll
  for (int i = 0; i < MI; ++i)
#pragma unroll
    for (int j = 0; j < NJ; ++j) acc[i][j] = (f32x4){0.f, 0.f, 0.f, 0.f};

  for (int k0 = 0; k0 < K; k0 += 64) {
    __syncthreads();
#pragma unroll
    for (int kk = 0; kk < 2; ++kk) {
#pragma unroll
      for (int s = 0; s < NSA; ++s) {
        int slot = s * 256 + tid;
        async_copy16(A + (size_t)(row0 + (slot >> 2)) * K + k0 + kk * 32 + (slot & 3) * 8,
                     &As[kk][slot * 8]);
      }
#pragma unroll
      for (int s = 0; s < NSB; ++s) {
        int slot = s * 256 + tid;
        async_copy16(B + (size_t)(col0 + (slot >> 2)) * K + k0 + kk * 32 + (slot & 3) * 8,
                     &Bs[kk][slot * 8]);
      }
    }
    __syncthreads();
#pragma unroll
    for (int kk = 0; kk < 2; ++kk) {
      bf16x8 a[MI], b[NJ];
#pragma unroll
      for (int i = 0; i < MI; ++i)
        a[i] = *(const bf16x8*)&As[kk][(wm + i * 16 + lanelow) * 32 + quad * 8];
#pragma unroll
      for (int j = 0; j < NJ; ++j)
        b[j] = *(const bf16x8*)&Bs[kk][(wn + j * 16 + lanelow) * 32 + quad * 8];
#pragma unroll
      for (int i = 0; i < MI; ++i)
#pragma unroll
        for (int j = 0; j < NJ; ++j)
          acc[i][j] = __builtin_amdgcn_mfma_f32_16x16x32_bf16(a[i], b[j], acc[i][j], 0, 0, 0);
    }
  }

#pragma unroll
  for (int i = 0; i < MI; ++i)
#pragma unroll
    for (int j = 0; j < NJ; ++j) {
      int r = row0 + wm + i * 16 + quad * 4;
      int c = col0 + wn + j * 16 + lanelow;
#pragma unroll
      for (int reg = 0; reg < 4; ++reg) {
        if (STORE_BF16)
          ((u16*)Cv)[(size_t)(r + reg) * N + c] = f2bf(acc[i][j][reg]);
        else
          ((float*)Cv)[(size_t)(r + reg) * N + c] = acc[i][j][reg];
      }
    }
}

// ---------------------------------------------------------------------------
// MFMA flash attention (unchanged from R9): 64-row q-tiles, S^T formulation
// (P in registers as B-operand of K=16 MFMA), fixed-shift softmax,
// double-buffered K/V with register prefetch, 1 barrier/k-tile.
// ---------------------------------------------------------------------------
__global__ __launch_bounds__(256) void attn_mfma(
    const u16* __restrict__ qa, const u16* __restrict__ ka,
    const u16* __restrict__ vt_g, u16* __restrict__ att)
{
  __shared__ u16 Ks[2][64 * PS];   // [buf][j][d]
  __shared__ u16 Vt[2][64 * PS];   // [buf][d][j]
  const int qt = blockIdx.x, h = blockIdx.y, b = blockIdx.z;
  const int hk = h >> 2;
  const int qb = qt * 64;
  const int tid = threadIdx.x;
  const int wave = tid >> 6, lane = tid & 63;
  const int quad = lane >> 4, lanelow = lane & 15;

  bf16x8 aQ[2];
#pragma unroll
  for (int kk = 0; kk < 2; ++kk)
    aQ[kk] = *(const bf16x8*)(qa +
        ((size_t)(b * T_LEN + qb + wave * 16 + lanelow) * HQn + h) * Dh +
        kk * 32 + quad * 8);

  f32x4 O[4];
  float l = 0.f;
#pragma unroll
  for (int dt = 0; dt < 4; ++dt) O[dt] = (f32x4){0.f, 0.f, 0.f, 0.f};

  const int kt0 = (qt >= 16) ? qt - 16 : 0;
  const int kt1 = qt;

  const int sr0 = tid >> 3,         sc0 = (tid & 7) * 8;
  const int sr1 = (tid + 256) >> 3, sc1 = ((tid + 256) & 7) * 8;
  const u16* kg = ka + (size_t)(b * T_LEN) * (HKn * Dh) + hk * Dh;
  const u16* vg = vt_g + (size_t)(b * HKn + hk) * Dh * T_LEN;

  {
    const int kb = kt0 * 64;
    uint4 k0 = *(const uint4*)(kg + (size_t)(kb + sr0) * (HKn * Dh) + sc0);
    uint4 k1 = *(const uint4*)(kg + (size_t)(kb + sr1) * (HKn * Dh) + sc1);
    uint4 v0 = *(const uint4*)(vg + (size_t)sr0 * T_LEN + kb + sc0);
    uint4 v1 = *(const uint4*)(vg + (size_t)sr1 * T_LEN + kb + sc1);
    *(uint4*)&Ks[0][sr0 * PS + sc0] = k0;
    *(uint4*)&Ks[0][sr1 * PS + sc1] = k1;
    *(uint4*)&Vt[0][sr0 * PS + sc0] = v0;
    *(uint4*)&Vt[0][sr1 * PS + sc1] = v1;
  }

  for (int kt = kt0; kt <= kt1; ++kt) {
    const int buf = (kt - kt0) & 1;
    const int kb = kt * 64;
    uint4 k0, k1, v0, v1;
    const bool more = (kt < kt1);
    if (more) {
      const int nb = kb + 64;
      k0 = *(const uint4*)(kg + (size_t)(nb + sr0) * (HKn * Dh) + sc0);
      k1 = *(const uint4*)(kg + (size_t)(nb + sr1) * (HKn * Dh) + sc1);
      v0 = *(const uint4*)(vg + (size_t)sr0 * T_LEN + nb + sc0);
      v1 = *(const uint4*)(vg + (size_t)sr1 * T_LEN + nb + sc1);
    }
    __syncthreads();

    f32x4 St[4];
#pragma unroll
    for (int jt = 0; jt < 4; ++jt) {
      bf16x8 aK0 = *(const bf16x8*)&Ks[buf][(jt * 16 + lanelow) * PS + quad * 8];
      bf16x8 aK1 = *(const bf16x8*)&Ks[buf][(jt * 16 + lanelow) * PS + 32 + quad * 8];
      f32x4 acc = (f32x4){-12.f, -12.f, -12.f, -12.f};
      acc = __builtin_amdgcn_mfma_f32_16x16x32_bf16(aK0, aQ[0], acc, 0, 0, 0);
      acc = __builtin_amdgcn_mfma_f32_16x16x32_bf16(aK1, aQ[1], acc, 0, 0, 0);
      St[jt] = acc;
    }
    if (kt == kt1) {
#pragma unroll
      for (int jt = 0; jt < 4; ++jt)
#pragma unroll
        for (int rr = 0; rr < 4; ++rr) {
          int ig = qb + wave * 16 + lanelow;
          int jg = kb + jt * 16 + quad * 4 + rr;
          if (jg > ig) St[jt][rr] = -1e30f;
        }
    } else if (kt == kt0 && qt >= 16) {
#pragma unroll
      for (int jt = 0; jt < 4; ++jt)
#pragma unroll
        for (int rr = 0; rr < 4; ++rr) {
          int ig = qb + wave * 16 + lanelow;
          int jg = kb + jt * 16 + quad * 4 + rr;
          if (jg < ig - WIN) St[jt][rr] = -1e30f;
        }
    }
    bf16x4 Pt[4];
#pragma unroll
    for (int jt = 0; jt < 4; ++jt) {
      float p0 = __builtin_amdgcn_exp2f(St[jt][0]);
      float p1 = __builtin_amdgcn_exp2f(St[jt][1]);
      float p2 = __builtin_amdgcn_exp2f(St[jt][2]);
      float p3 = __builtin_amdgcn_exp2f(St[jt][3]);
      l += (p0 + p1) + (p2 + p3);
      union { uint2 u; bf16x4 v; } pu;
      pu.u.x = pack_bf2(p1, p0);
      pu.u.y = pack_bf2(p3, p2);
      Pt[jt] = pu.v;
    }
#pragma unroll
    for (int dt = 0; dt < 4; ++dt)
#pragma unroll
      for (int jt = 0; jt < 4; ++jt) {
        bf16x4 aV = *(const bf16x4*)&Vt[buf][(dt * 16 + lanelow) * PS + jt * 16 + quad * 4];
        O[dt] = MFMA16(aV, Pt[jt], O[dt]);
      }
    if (more) {
      const int nbuf = buf ^ 1;
      *(uint4*)&Ks[nbuf][sr0 * PS + sc0] = k0;
      *(uint4*)&Ks[nbuf][sr1 * PS + sc1] = k1;
      *(uint4*)&Vt[nbuf][sr0 * PS + sc0] = v0;
      *(uint4*)&Vt[nbuf][sr1 * PS + sc1] = v1;
    }
  }

  {
    float s = l;
    s += __shfl_xor(s, 16, 64);
    s += __shfl_xor(s, 32, 64);
    float inv = 1.f / s;
    int qg = qb + wave * 16 + lanelow;
    u16* obase = att + (size_t)(b * T_LEN + qg) * E_DIM + h * Dh;
#pragma unroll
    for (int dt = 0; dt < 4; ++dt) {
      bf16x4 ov;
      ov[0] = (short)f2bf(O[dt][0] * inv);
      ov[1] = (short)f2bf(O[dt][1] * inv);
      ov[2] = (short)f2bf(O[dt][2] * inv);
      ov[3] = (short)f2bf(O[dt][3] * inv);
      *(bf16x4*)(obase + dt * 16 + quad * 4) = ov;
    }
  }
}

// ---------------------------------------------------------------------------
extern "C" void kernel_launch(void* const* d_in, const int* in_sizes, int n_in,
                              void* d_out, int out_size, void* d_ws, size_t ws_size,
                              hipStream_t stream)
{
  const float* x    = (const float*)d_in[0];
  const float* ve   = (const float*)d_in[1];
  const float* rc   = (const float*)d_in[2];
  const float* rs   = (const float*)d_in[3];
  const float* wqkv = (const float*)d_in[4];
  const float* wg   = (const float*)d_in[5];
  const float* wo   = (const float*)d_in[6];
  float* out = (float*)d_out;

  char* ws = (char*)d_ws;
  // ws layout — ALL ranges disjoint (R8 lesson):
  //   [0,        8388608)  x_bf      4096x1024 bf16
  //   [8388608, 11534336)  wqkv_bf   1536x1024 bf16
  //   [11534336,13631488)  wo_bf     1024x1024 bf16
  //   [13631488,22020096)  q_att     4096x16x64 bf16
  //   [22020096,24117248)  k_att     4096x4x64 bf16
  //   [24117248,26214400)  v_t       (2*4*64)x2048 bf16
  //   [26214400,34603008)  att       4096x1024 bf16
  u16* x_bf    = (u16*)(ws);
  u16* wqkv_bf = (u16*)(ws + 8388608);
  u16* wo_bf   = (u16*)(ws + 11534336);
  u16* q_att   = (u16*)(ws + 13631488);
  u16* k_att   = (u16*)(ws + 22020096);
  u16* v_t     = (u16*)(ws + 24117248);
  u16* att     = (u16*)(ws + 26214400);

  cvt_all<<<6656, 256, 0, stream>>>((const float4*)x, (const float4*)wqkv,
                                    (const float4*)wo, (uint2*)x_bf,
                                    (uint2*)wqkv_bf, (uint2*)wo_bf);
  gemm_qkv<<<dim3(64, 24), 256, 0, stream>>>(x_bf, wqkv_bf, x, ve, rc, rs, wg,
                                             q_att, k_att, v_t);
  attn_mfma<<<dim3(T_LEN / 64, HQn, NB), 256, 0, stream>>>(q_att, k_att, v_t, att);
  gemm_async<64, 64, 0><<<dim3(64, 16), 256, 0, stream>>>(
      att, wo_bf, out, 4096, E_DIM, E_DIM);
}